// Round 2
// baseline (94.785 us; speedup 1.0000x reference)
//
#include <hip/hip_runtime.h>
#include <hip/hip_bf16.h>

// Problem: RvNN_BU_84911503442503
// Key insight: the reference's scan over nodes is dead code (h_copy is deleted;
// the head reads the ORIGINAL h_e[:,0,:]). Live computation:
//   y[b,c] = b_fc[c] + sum_o W_fc[c,o] * ( sum_f h[b,0,f] * W_emb[o,f] )
// Shapes: B=32, N=128, FI=768, FO=128, output [32,2].
// Dtypes: ALL float32 (reference is jnp.float32; round-1 NaN proved inputs are
// not bf16 — reading f32 bits as bf16 produced NaN patterns).

#define BB 32
#define NN 128
#define FI 768
#define FO 128

__global__ __launch_bounds__(FO) void rvnn_head_kernel(
    const float* __restrict__ h,      // [B,N,FI]
    const float* __restrict__ W_emb,  // [FO,FI]
    const float* __restrict__ W_fc,   // [2,FO]
    const float* __restrict__ b_fc,   // [2]
    float* __restrict__ out)          // [B,2]
{
    __shared__ float h0[FI];
    __shared__ float he[FO];

    const int b   = blockIdx.x;
    const int tid = threadIdx.x;   // 0..127 = output feature o

    // Stage h[b,0,:] into LDS (node 0 row), coalesced.
    const float* hrow = h + (size_t)b * NN * FI;
#pragma unroll
    for (int f = tid; f < FI; f += FO)
        h0[f] = hrow[f];
    __syncthreads();

    // h_e[b,0,tid] = dot(h0, W_emb[tid,:]) — 768-length dot, float4 loads.
    const float4* wv = reinterpret_cast<const float4*>(W_emb + (size_t)tid * FI);
    float acc = 0.f;
#pragma unroll 8
    for (int i = 0; i < FI / 4; ++i) {
        float4 p = wv[i];
        const float* hp = &h0[i * 4];
        acc += hp[0] * p.x;
        acc += hp[1] * p.y;
        acc += hp[2] * p.z;
        acc += hp[3] * p.w;
    }
    he[tid] = acc;
    __syncthreads();

    // Final head: y[b,c] = b_fc[c] + dot(W_fc[c,:], he)
    if (tid < 2) {
        float y = b_fc[tid];
        const float* wfc = W_fc + tid * FO;
#pragma unroll 8
        for (int o = 0; o < FO; ++o)
            y += wfc[o] * he[o];
        out[b * 2 + tid] = y;
    }
}

extern "C" void kernel_launch(void* const* d_in, const int* in_sizes, int n_in,
                              void* d_out, int out_size, void* d_ws, size_t ws_size,
                              hipStream_t stream) {
    // setup_inputs() order:
    // 0:h 1:adj 2:W_emb 3:W_ioux 4:b_ioux 5:W_iouh 6:b_iouh
    // 7:W_coux 8:b_coux 9:W_couh 10:b_couh 11:W_fc 12:b_fc
    const float* h     = (const float*)d_in[0];
    const float* W_emb = (const float*)d_in[2];
    const float* W_fc  = (const float*)d_in[11];
    const float* b_fc  = (const float*)d_in[12];
    float* out = (float*)d_out;

    rvnn_head_kernel<<<BB, FO, 0, stream>>>(h, W_emb, W_fc, b_fc, out);
}